// Round 1
// baseline (2009.346 us; speedup 1.0000x reference)
//
#include <hip/hip_runtime.h>
#include <math.h>

// LSTM: B=64, T=2048, I=200, H=100. Output h_T [64,100] fp32.
//   prep_kernel : transpose W_ih -> Wt[200][512], bias = b_ih+b_hh,
//                 Whh_pad[400][104] (k padded 100->104 with zeros)
//   xproj_kernel: xg[b,t,g] = x[b,t,:].Wt[:,g] + bias[g]  (fp32, pk_fma packed)
//   lstm_kernel : 64 WGs (one per batch), 256 thr (4 waves). Thread (q=tid>>1,
//                 s2=tid&1) owns ALL 4 gates of hidden unit q over HALF of h
//                 (52 elems). h broadcast = 13 ds_read_b128/thread (52 instr/CU/step
//                 vs 350 b64 before). Pair-reduce via one quad DPP swap per gate;
//                 both lanes redundantly compute c,h. One barrier/step.

#define T_TOTAL 2048
#define B_SZ 64
#define IN_SZ 200
#define H_SZ 100
#define GP 512  // padded gate dim (4*H=400 -> 512)
#define KP 104  // padded hidden dim for Whh rows (100 -> 104)

typedef float v2f __attribute__((ext_vector_type(2)));

__device__ __forceinline__ float sigf(float x) {
    return __builtin_amdgcn_rcpf(1.f + __expf(-x));
}

// swap adjacent lanes within each quad: [1,0,3,2]
#define DPP_SWAP(x) \
    __int_as_float(__builtin_amdgcn_mov_dpp(__float_as_int(x), 0xB1, 0xF, 0xF, true))

// ---------------- prep ----------------
__global__ void prep_kernel(const float* __restrict__ W_ih,
                            const float* __restrict__ W_hh,
                            const float* __restrict__ b_ih,
                            const float* __restrict__ b_hh,
                            float* __restrict__ Wt,
                            float* __restrict__ bias,
                            float* __restrict__ Whp) {
    int idx = blockIdx.x * 256 + threadIdx.x;
    if (idx < IN_SZ * GP) {
        int k = idx >> 9;
        int g = idx & (GP - 1);
        Wt[idx] = (g < 400) ? W_ih[g * IN_SZ + k] : 0.f;
    }
    if (idx < GP) bias[idx] = (idx < 400) ? (b_ih[idx] + b_hh[idx]) : 0.f;
    if (idx < 400 * KP) {
        int g = idx / KP;
        int k = idx - g * KP;
        Whp[idx] = (k < H_SZ) ? W_hh[g * H_SZ + k] : 0.f;
    }
}

// ---------------- input projection GEMM (pk_fma packed) ----------------
__global__ __launch_bounds__(256, 4) void xproj_kernel(
    const float* __restrict__ x, const float* __restrict__ Wt,
    const float* __restrict__ bias, float* __restrict__ xg,
    int t0, int Tlen) {
    __shared__ __align__(16) float xTc[50][68];
    __shared__ __align__(16) float4 LW[50][32];

    const int tid = threadIdx.x;
    const int gblk = blockIdx.x;
    const int tbase = t0 + blockIdx.y * 64;
    const int b = blockIdx.z;
    const int gt = tid & 15;
    const int tt = tid >> 4;

    v2f acc[4][4];
#pragma unroll
    for (int r = 0; r < 4; ++r)
#pragma unroll
        for (int h = 0; h < 4; ++h) { acc[r][h].x = 0.f; acc[r][h].y = 0.f; }

    const float2* x2 = (const float2*)x;
    const float4* Wt4 = (const float4*)Wt;

    for (int kc = 0; kc < 4; ++kc) {
        for (int idx = tid; idx < 64 * 25; idx += 256) {
            int row = idx / 25, c2 = idx % 25;
            float2 v = x2[(size_t)(b * T_TOTAL + tbase + row) * (IN_SZ / 2) + kc * 25 + c2];
            xTc[c2 * 2][row] = v.x;
            xTc[c2 * 2 + 1][row] = v.y;
        }
        for (int idx = tid; idx < 50 * 32; idx += 256) {
            int k = idx >> 5, c = idx & 31;
            LW[k][c] = Wt4[(size_t)(kc * 50 + k) * (GP / 4) + gblk * 32 + c];
        }
        __syncthreads();

#pragma unroll 5
        for (int k = 0; k < 50; ++k) {
            float4 xv = *(const float4*)&xTc[k][tt * 4];
            float4 w0 = LW[k][gt];
            float4 w1 = LW[k][16 + gt];
            v2f wv[4];
            wv[0].x = w0.x; wv[0].y = w0.y; wv[1].x = w0.z; wv[1].y = w0.w;
            wv[2].x = w1.x; wv[2].y = w1.y; wv[3].x = w1.z; wv[3].y = w1.w;
            float xa[4] = {xv.x, xv.y, xv.z, xv.w};
#pragma unroll
            for (int tr = 0; tr < 4; ++tr) {
                v2f xs; xs.x = xa[tr]; xs.y = xa[tr];
#pragma unroll
                for (int h = 0; h < 4; ++h)
                    acc[tr][h] = __builtin_elementwise_fma(xs, wv[h], acc[tr][h]);
            }
        }
        __syncthreads();
    }

    const float4* bias4 = (const float4*)bias;
    float4 b0 = bias4[gblk * 32 + gt];
    float4 b1 = bias4[gblk * 32 + 16 + gt];
    float4* o4 = (float4*)xg;
#pragma unroll
    for (int tr = 0; tr < 4; ++tr) {
        int trow = (tbase - t0) + tt * 4 + tr;
        size_t o = (size_t)(b * Tlen + trow) * (GP / 4) + gblk * 32;
        float4 v0 = make_float4(acc[tr][0].x + b0.x, acc[tr][0].y + b0.y,
                                acc[tr][1].x + b0.z, acc[tr][1].y + b0.w);
        float4 v1 = make_float4(acc[tr][2].x + b1.x, acc[tr][2].y + b1.y,
                                acc[tr][3].x + b1.z, acc[tr][3].y + b1.w);
        o4[o + gt] = v0;
        o4[o + 16 + gt] = v1;
    }
}

// ---------------- recurrence: one WG (256 thr) per batch ----------------
// Thread (q = tid>>1 < 100, s2 = tid&1) owns gates {q, 100+q, 200+q, 300+q}
// over h-half s2 (k in [s2*52, s2*52+52), zero-padded). Per step:
//   13 x ds_read_b128 of h-half, 104 x v_pk_fma_f32 (4 gates x 26),
//   per-gate pair-reduce via quad DPP swap, activations, c/h update (both lanes),
//   s2==0 writes h_q to the other LDS buffer, ONE __syncthreads per step.
__global__ __attribute__((amdgpu_flat_work_group_size(256, 256), amdgpu_waves_per_eu(1, 1)))
void lstm_kernel(
    const float* __restrict__ xg, const float* __restrict__ Whp,
    float* __restrict__ hstate, float* __restrict__ cstate,
    float* __restrict__ out, int Tlen, int first, int last) {
    __shared__ __align__(16) float hlds[2][KP];  // double-buffered h[100] + pad

    const int b = blockIdx.x;
    const int tid = threadIdx.x;
    const int q = tid >> 1;
    const int s2 = tid & 1;
    const bool active = (q < H_SZ);

    // 4 gate half-rows: 4 x 26 v2f = 208 VGPRs, kept resident (waves_per_eu(1,1)).
    v2f w[4][26];
    if (active) {
        const v2f* W2 = (const v2f*)Whp;
#pragma unroll
        for (int g = 0; g < 4; ++g) {
            const v2f* row = W2 + (size_t)(g * H_SZ + q) * (KP / 2) + s2 * 26;
#pragma unroll
            for (int m = 0; m < 26; ++m) w[g][m] = row[m];
        }
    } else {
#pragma unroll
        for (int g = 0; g < 4; ++g)
#pragma unroll
            for (int m = 0; m < 26; ++m) { w[g][m].x = 0.f; w[g][m].y = 0.f; }
    }

    float c = 0.f;
    if (active) c = first ? 0.f : cstate[b * H_SZ + q];
    if (tid < KP) hlds[0][tid] = (tid < H_SZ) ? (first ? 0.f : hstate[b * H_SZ + tid]) : 0.f;
    if (tid < KP - H_SZ) hlds[1][H_SZ + tid] = 0.f;  // zero pad of buffer 1
    __syncthreads();

    const size_t base = (size_t)b * Tlen * GP;
    float xv[4], xn[4];
#pragma unroll
    for (int g = 0; g < 4; ++g)
        xv[g] = active ? xg[base + g * H_SZ + q] : 0.f;

    float hval = 0.f;
    for (int tl = 0; tl < Tlen; ++tl) {
        const bool pf = active && (tl + 1) < Tlen;
        const size_t nbase = base + (size_t)(tl + 1) * GP;
#pragma unroll
        for (int g = 0; g < 4; ++g) xn[g] = pf ? xg[nbase + g * H_SZ + q] : 0.f;

        const float4* hb4 = (const float4*)&hlds[tl & 1][s2 * 52];
        v2f a0[4], a1[4];
#pragma unroll
        for (int g = 0; g < 4; ++g) {
            a0[g].x = 0.f; a0[g].y = 0.f;
            a1[g].x = 0.f; a1[g].y = 0.f;
        }
#pragma unroll
        for (int m = 0; m < 13; ++m) {
            float4 h4 = hb4[m];
            v2f hlo; hlo.x = h4.x; hlo.y = h4.y;
            v2f hhi; hhi.x = h4.z; hhi.y = h4.w;
#pragma unroll
            for (int g = 0; g < 4; ++g) {
                a0[g] = __builtin_elementwise_fma(hlo, w[g][2 * m], a0[g]);
                a1[g] = __builtin_elementwise_fma(hhi, w[g][2 * m + 1], a1[g]);
            }
        }

        float d[4];
#pragma unroll
        for (int g = 0; g < 4; ++g) {
            v2f sv = a0[g] + a1[g];
            float p = sv.x + sv.y;
            d[g] = p + DPP_SWAP(p) + xv[g];
        }

        float ai = sigf(d[0]);
        float af = sigf(d[1]);
        float ag = __builtin_fmaf(sigf(2.f * d[2]), 2.f, -1.f);  // tanh
        float ao = sigf(d[3]);
        c = __builtin_fmaf(af, c, ai * ag);
        float tc = __builtin_fmaf(sigf(2.f * c), 2.f, -1.f);     // tanh(c)
        hval = ao * tc;

        if (active && s2 == 0) hlds[(tl & 1) ^ 1][q] = hval;
        __syncthreads();
#pragma unroll
        for (int g = 0; g < 4; ++g) xv[g] = xn[g];
    }

    if (active && s2 == 0) {
        hstate[b * H_SZ + q] = hval;
        cstate[b * H_SZ + q] = c;
        if (last) out[b * H_SZ + q] = hval;
    }
}

// ---------------- host ----------------
extern "C" void kernel_launch(void* const* d_in, const int* in_sizes, int n_in,
                              void* d_out, int out_size, void* d_ws, size_t ws_size,
                              hipStream_t stream) {
    const float* x    = (const float*)d_in[0];
    const float* W_ih = (const float*)d_in[1];
    const float* W_hh = (const float*)d_in[2];
    const float* b_ih = (const float*)d_in[3];
    const float* b_hh = (const float*)d_in[4];
    float* out = (float*)d_out;

    char* ws = (char*)d_ws;
    float* Wt     = (float*)(ws);            // 200*512*4      = 409600
    float* bias   = (float*)(ws + 409600);   // 512*4          = 2048
    float* Whp    = (float*)(ws + 411648);   // 400*104*4      = 166400
    float* hstate = (float*)(ws + 578048);   // 64*100*4       = 25600
    float* cstate = (float*)(ws + 603648);   // 64*100*4       = 25600
    float* xgbuf  = (float*)(ws + 629248);

    size_t cap = (ws_size > 629248) ? (ws_size - 629248) : 0;
    long long tcmax = (long long)(cap / ((size_t)B_SZ * GP * 4));
    int Tc = (int)((tcmax / 64) * 64);
    if (Tc > T_TOTAL) Tc = T_TOTAL;
    if (Tc < 64) Tc = 64;

    prep_kernel<<<400, 256, 0, stream>>>(W_ih, W_hh, b_ih, b_hh, Wt, bias, Whp);

    for (int t0 = 0; t0 < T_TOTAL; t0 += Tc) {
        int Tlen = T_TOTAL - t0;
        if (Tlen > Tc) Tlen = Tc;
        xproj_kernel<<<dim3(4, Tlen / 64, B_SZ), 256, 0, stream>>>(x, Wt, bias, xgbuf, t0, Tlen);
        lstm_kernel<<<B_SZ, 256, 0, stream>>>(xgbuf, Whp, hstate, cstate, out,
                                              Tlen, t0 == 0 ? 1 : 0,
                                              (t0 + Tlen) == T_TOTAL ? 1 : 0);
    }
}